// Round 3
// baseline (345.916 us; speedup 1.0000x reference)
//
#include <hip/hip_runtime.h>
#include <hip/hip_bf16.h>
#include <math.h>

#define QN 128
#define SN 128
#define HN 32
#define CN (QN * SN)
#define BBLK 256   // batch rows per block (4 groups of 64)

typedef unsigned int u32;

// Direct global->LDS (no VGPR roundtrip). LDS dest must be wave-uniform base;
// HW adds lane*16B. Size arg must be a literal.
__device__ __forceinline__ void gload16(const float* g, float* l) {
  __builtin_amdgcn_global_load_lds(
      (const __attribute__((address_space(1))) u32*)(const void*)g,
      (__attribute__((address_space(3))) u32*)(void*)l,
      16, 0, 0);
}

// Block: 256 threads (4 waves), one q, 256 batch rows.
// Row-group = 64 rows; half-tile = 64 rows x 64 s-floats = 16 KB, double-buffered.
// Compute: lane = row (0..63), wave w owns h-octet h0=w*8 -> W1/b1/W2 operands
// are wave-uniform (SGPR broadcast). x staged via global_load_lds with the
// global source pre-swizzled by (slot ^ (row&7)); reads apply the same XOR,
// so each lane reads its own row's s-quad conflict-free AND all lanes hold the
// same global s (keeping W1 scalar).
__global__ __launch_bounds__(256, 4)
void divenc_kernel(const float* __restrict__ x,
                   const float* __restrict__ W1,
                   const float* __restrict__ b1,
                   const float* __restrict__ W2,
                   const float* __restrict__ b2,
                   float* __restrict__ out) {
  const int q    = blockIdx.x;
  const int b0   = blockIdx.y * BBLK;
  const int tid  = threadIdx.x;
  const int lane = tid & 63;
  const int wid  = __builtin_amdgcn_readfirstlane(tid >> 6);
  const int h0   = wid * 8;  // uniform per wave

  __shared__ float xs[2][64 * 64];  // two 16 KB half-tile buffers
  __shared__ float parts[4][64];

  const float* __restrict__ w1q = W1 + (size_t)q * (SN * HN);

  float b1v[8], w2v[8];
  #pragma unroll
  for (int j = 0; j < 8; ++j) {
    b1v[j] = b1[q * HN + h0 + j];   // uniform -> s_load
    w2v[j] = W2[q * HN + h0 + j];
  }
  const float b2q = b2[q];

  const float* xqbase = x + (size_t)b0 * CN + (size_t)q * SN;

  // Stage half-tile ht (0..7): group g=ht>>1, half=ht&1, into xs[ht&1].
  // Wave w stages rows w*16..w*16+15 with 4 calls of 1 KB (4 rows) each.
  auto STAGE = [&](int ht) {
    const int g = ht >> 1, half = ht & 1;
    float* buf = xs[ht & 1];
    #pragma unroll
    for (int k = 0; k < 4; ++k) {
      const int rloc = wid * 16 + k * 4 + (lane >> 4);
      const int slot = lane & 15;
      const int scol = (half << 6) + ((slot ^ (rloc & 7)) << 2);
      const float* gp = xqbase + (size_t)(g * 64 + rloc) * CN + scol;
      gload16(gp, buf + (wid * 16 + k * 4) * 64);
    }
  };

  STAGE(0);
  __syncthreads();  // drains vmcnt(0)

  const int xr7 = lane & 7;

  #pragma unroll 1
  for (int g = 0; g < 4; ++g) {
    float acc[8];
    #pragma unroll
    for (int j = 0; j < 8; ++j) acc[j] = 0.f;

    #pragma unroll
    for (int half = 0; half < 2; ++half) {
      const int ht = g * 2 + half;
      if (ht < 7) STAGE(ht + 1);  // async prefetch into other buffer

      const float* xrow = xs[ht & 1] + lane * 64;
      #pragma unroll
      for (int sq = 0; sq < 16; ++sq) {
        const float4 xv =
            *reinterpret_cast<const float4*>(xrow + ((sq ^ xr7) << 2));
        const float* __restrict__ wrow =
            w1q + ((half << 6) + (sq << 2)) * HN + h0;  // uniform addr
        #pragma unroll
        for (int u = 0; u < 4; ++u) {
          const float xu = (&xv.x)[u];
          #pragma unroll
          for (int j = 0; j < 8; ++j)
            acc[j] = fmaf(xu, wrow[u * HN + j], acc[j]);
        }
      }

      if (half == 1) {
        float part = 0.f;
        #pragma unroll
        for (int j = 0; j < 8; ++j) {
          float v = acc[j] + b1v[j];
          v = v > 0.f ? v : expm1f(v);
          part = fmaf(v, w2v[j], part);
        }
        parts[wid][lane] = part;
      }

      __syncthreads();  // drains vmcnt (prefetch done) + makes parts visible

      if (half == 1 && wid == 0) {
        const float o = parts[0][lane] + parts[1][lane] + parts[2][lane] +
                        parts[3][lane] + b2q;
        out[(size_t)(b0 + g * 64 + lane) * QN + q] = o;
      }
    }
  }
}

extern "C" void kernel_launch(void* const* d_in, const int* in_sizes, int n_in,
                              void* d_out, int out_size, void* d_ws, size_t ws_size,
                              hipStream_t stream) {
  const float* x  = (const float*)d_in[0];
  const float* W1 = (const float*)d_in[1];
  const float* b1 = (const float*)d_in[2];
  const float* W2 = (const float*)d_in[3];
  const float* b2 = (const float*)d_in[4];
  float* out = (float*)d_out;

  const int B = in_sizes[0] / CN;  // 2048
  dim3 grid(QN, B / BBLK);
  divenc_kernel<<<grid, 256, 0, stream>>>(x, W1, b1, W2, b2, out);
}

// Round 4
// 65.011 us; speedup vs baseline: 5.3208x; 5.3208x over previous
//
#include <hip/hip_runtime.h>
#include <hip/hip_bf16.h>
#include <math.h>

#define QN 128
#define SN 128
#define HN 32
#define CN (QN * SN)
#define TILE_R 64
#define NTILE 4
#define BBLK (TILE_R * NTILE)  // 256 batch rows per block

// Block: 256 threads (4 waves), one q, 256 batch rows in 4 tiles of 64.
// Compute: lane = row (0..63), wave w owns h-octet h0 = w*8 -> all W1/b1/W2
// operands are wave-uniform (SGPR broadcast, s_load). x staged coalesced into
// XOR-swizzled LDS (proven 0 bank conflicts in round 2). NO register-carried
// prefetch: load->ds_write has short register liveness; TLP (4 blocks/CU)
// hides the per-tile VMEM latency.
__global__ __launch_bounds__(256, 4)
void divenc_kernel(const float* __restrict__ x,
                   const float* __restrict__ W1,
                   const float* __restrict__ b1,
                   const float* __restrict__ W2,
                   const float* __restrict__ b2,
                   float* __restrict__ out) {
  const int q    = blockIdx.x;
  const int b0   = blockIdx.y * BBLK;
  const int tid  = threadIdx.x;
  const int lane = tid & 63;
  const int wid  = __builtin_amdgcn_readfirstlane(tid >> 6);
  const int h0   = wid * 8;  // uniform per wave

  __shared__ float xtile[TILE_R * SN];  // 32 KB, XOR-swizzled rows
  __shared__ float parts[4][TILE_R];

  const float* __restrict__ w1q = W1 + (size_t)q * (SN * HN);

  float b1v[8], w2v[8];
  #pragma unroll
  for (int j = 0; j < 8; ++j) {
    b1v[j] = b1[q * HN + h0 + j];   // uniform -> s_load
    w2v[j] = W2[q * HN + h0 + j];
  }
  const float b2q = b2[q];

  const float* xbase = x + (size_t)b0 * CN + (size_t)q * SN;

  #pragma unroll 1
  for (int t = 0; t < NTILE; ++t) {
    // ---- stage tile t: coalesced (each instr = 8 contiguous 512B row segs),
    // written immediately to swizzled LDS (no long-lived registers).
    const float* tb = xbase + (size_t)t * TILE_R * CN;
    #pragma unroll
    for (int i = 0; i < 8; ++i) {
      const int f = i * 256 + tid;
      const int r = f >> 5, c = f & 31;
      const float4 vv = *reinterpret_cast<const float4*>(tb + (size_t)r * CN + c * 4);
      *reinterpret_cast<float4*>(&xtile[r * SN + ((c ^ (r & 31)) << 2)]) = vv;
    }
    __syncthreads();

    // ---- compute: lane's row from LDS, W1 broadcast from SGPRs
    float acc[8];
    #pragma unroll
    for (int j = 0; j < 8; ++j) acc[j] = 0.f;

    #pragma unroll 2
    for (int s4 = 0; s4 < SN; s4 += 4) {
      const float4 xv = *reinterpret_cast<const float4*>(
          &xtile[(lane << 7) + (((s4 >> 2) ^ (lane & 31)) << 2)]);
      #pragma unroll
      for (int u = 0; u < 4; ++u) {
        const float xu = (&xv.x)[u];
        const float* __restrict__ wrow = w1q + (s4 + u) * HN + h0;  // uniform
        #pragma unroll
        for (int j = 0; j < 8; ++j)
          acc[j] = fmaf(xu, wrow[j], acc[j]);
      }
    }

    // ---- epilogue: +b1, ELU, dot W2 over this wave's 8 h
    float part = 0.f;
    #pragma unroll
    for (int j = 0; j < 8; ++j) {
      float v = acc[j] + b1v[j];
      v = v > 0.f ? v : expm1f(v);
      part = fmaf(v, w2v[j], part);
    }
    parts[wid][lane] = part;
    __syncthreads();  // all compute reads of xtile done; parts visible

    if (wid == 0) {
      const float o = parts[0][lane] + parts[1][lane] + parts[2][lane] +
                      parts[3][lane] + b2q;
      out[(size_t)(b0 + t * TILE_R + lane) * QN + q] = o;
    }
    // Safe without a third sync: between here and the next parts-store,
    // other waves only overwrite xtile (guarded by the staging sync above).
  }
}

extern "C" void kernel_launch(void* const* d_in, const int* in_sizes, int n_in,
                              void* d_out, int out_size, void* d_ws, size_t ws_size,
                              hipStream_t stream) {
  const float* x  = (const float*)d_in[0];
  const float* W1 = (const float*)d_in[1];
  const float* b1 = (const float*)d_in[2];
  const float* W2 = (const float*)d_in[3];
  const float* b2 = (const float*)d_in[4];
  float* out = (float*)d_out;

  const int B = in_sizes[0] / CN;  // 2048
  dim3 grid(QN, B / BBLK);
  divenc_kernel<<<grid, 256, 0, stream>>>(x, W1, b1, W2, b2, out);
}